// Round 4
// baseline (249.291 us; speedup 1.0000x reference)
//
#include <hip/hip_runtime.h>
#include <hip/hip_bf16.h>
#include <cstdio>

#define B_  64
#define I_  2048
#define J_  16
#define N_  64
#define D_  16
#define K_  1024   // N_*D_

typedef __attribute__((ext_vector_type(8))) unsigned short ushort8_t;

__device__ __forceinline__ float bf2f(unsigned short h) {
  return __uint_as_float(((unsigned int)h) << 16);
}

// One block per in_capsule i (grid 2048), all 64 batches per block.
// W[i] slice in registers (16 float4/thread); x rows (64 b x 16 j, 4 KB) in LDS,
// read as ds_read_b128 broadcasts with a 1-deep next-b software pipeline.
// fp32->bf16 via v_cvt_pk (__float22bfloat162_rn), ushort4 (8 B) coalesced stores.
__global__ __launch_bounds__(256) void project_k(const float* __restrict__ x,
                                                 const float* __restrict__ W,
                                                 unsigned short* __restrict__ uh) {
  const int i = blockIdx.x;
  const int t = threadIdx.x;

  __shared__ float4 xl[B_ * 4];        // 4 KB: x[bb][i][0..15] as 4 float4 per b
  {
    int bb = t >> 2, q = t & 3;        // 256 threads cover 64 b x 4 quads exactly
    xl[t] = ((const float4*)(x + ((size_t)bb * I_ + i) * J_))[q];
  }

  const float4* Wp = (const float4*)(W + (size_t)i * (J_ * K_));
  float4 w[J_];
#pragma unroll
  for (int j = 0; j < J_; ++j) w[j] = Wp[j * (K_ / 4) + t];

  __syncthreads();

  unsigned short* op = uh + (size_t)i * K_ + t * 4;

  float4 xa0 = xl[0], xa1 = xl[1], xa2 = xl[2], xa3 = xl[3];
  for (int bb = 0; bb < B_; ++bb) {
    float4 xb0, xb1, xb2, xb3;
    if (bb < B_ - 1) {                  // prefetch next b's x (4x ds_read_b128)
      xb0 = xl[(bb + 1) * 4 + 0]; xb1 = xl[(bb + 1) * 4 + 1];
      xb2 = xl[(bb + 1) * 4 + 2]; xb3 = xl[(bb + 1) * 4 + 3];
    }
    float4 acc = {0.f, 0.f, 0.f, 0.f};
#define FMA4(xc, j0)  \
    acc.x += xc.x * w[j0].x;     acc.y += xc.x * w[j0].y;     acc.z += xc.x * w[j0].z;     acc.w += xc.x * w[j0].w; \
    acc.x += xc.y * w[j0+1].x;   acc.y += xc.y * w[j0+1].y;   acc.z += xc.y * w[j0+1].z;   acc.w += xc.y * w[j0+1].w; \
    acc.x += xc.z * w[j0+2].x;   acc.y += xc.z * w[j0+2].y;   acc.z += xc.z * w[j0+2].z;   acc.w += xc.z * w[j0+2].w; \
    acc.x += xc.w * w[j0+3].x;   acc.y += xc.w * w[j0+3].y;   acc.z += xc.w * w[j0+3].z;   acc.w += xc.w * w[j0+3].w;
    FMA4(xa0, 0) FMA4(xa1, 4) FMA4(xa2, 8) FMA4(xa3, 12)
#undef FMA4
    // fp32 -> bf16 RNE via v_cvt_pk_bf16_f32
    __hip_bfloat162 p0 = __float22bfloat162_rn(float2{acc.x, acc.y});
    __hip_bfloat162 p1 = __float22bfloat162_rn(float2{acc.z, acc.w});
    uint2 st;
    st.x = *(unsigned int*)&p0;
    st.y = *(unsigned int*)&p1;
    *(uint2*)op = st;
    op += (size_t)I_ * K_;
    xa0 = xb0; xa1 = xb1; xa2 = xb2; xa3 = xb3;
  }
}

// Wave-local routing: lane = class capsule n; lane owns u[b,i,n*16..n*16+15].
// Softmax over n == 6-step __shfl_xor reduce. ZERO barriers in main loop.
// squash(v) computed INLINE from raw s buffers (lane-local: 16 d per lane).
// MODE 0: c = 1/64 exactly -> plain sum * 1/64.
// MODE 1: logit = dot(u, v0),          v0 = squash(s0 + bias)
// MODE 2: logit = dot(u, v0)+dot(u,v1) (b-logits recomputed, never materialized)
template <int MODE>
__global__ __launch_bounds__(256, 4) void route_k(const unsigned short* __restrict__ uh,
                                                  const float* __restrict__ sa,
                                                  const float* __restrict__ sb,
                                                  const float* __restrict__ bias,
                                                  float* __restrict__ s_out) {
  const int t    = threadIdx.x;
  const int lane = t & 63;            // = n
  const int wv   = t >> 6;            // 0..3
  const int b    = blockIdx.x >> 4;                 // 16 blocks per batch
  const int iw   = ((blockIdx.x & 15) << 2) + wv;   // 0..63
  const int i0   = iw * 32;                         // 32 i per wave

  float va_r[16], vb_r[16];
  if (MODE >= 1) {
    float bs[16];
#pragma unroll
    for (int q = 0; q < 4; ++q) {
      float4 bb4 = *(const float4*)&bias[lane * 16 + q * 4];
      bs[q*4+0] = bb4.x; bs[q*4+1] = bb4.y; bs[q*4+2] = bb4.z; bs[q*4+3] = bb4.w;
    }
    {
      float nn = 0.f;
#pragma unroll
      for (int q = 0; q < 4; ++q) {
        float4 tmp = *(const float4*)&sa[(size_t)b * K_ + lane * 16 + q * 4];
        va_r[q*4+0] = tmp.x + bs[q*4+0]; va_r[q*4+1] = tmp.y + bs[q*4+1];
        va_r[q*4+2] = tmp.z + bs[q*4+2]; va_r[q*4+3] = tmp.w + bs[q*4+3];
      }
#pragma unroll
      for (int d = 0; d < 16; ++d) nn += va_r[d] * va_r[d];
      float n2 = nn + 1e-7f;
      float f = sqrtf(n2) / (1.0f + n2);
#pragma unroll
      for (int d = 0; d < 16; ++d) va_r[d] *= f;
    }
    if (MODE == 2) {
      float nn = 0.f;
#pragma unroll
      for (int q = 0; q < 4; ++q) {
        float4 tmp = *(const float4*)&sb[(size_t)b * K_ + lane * 16 + q * 4];
        vb_r[q*4+0] = tmp.x + bs[q*4+0]; vb_r[q*4+1] = tmp.y + bs[q*4+1];
        vb_r[q*4+2] = tmp.z + bs[q*4+2]; vb_r[q*4+3] = tmp.w + bs[q*4+3];
      }
#pragma unroll
      for (int d = 0; d < 16; ++d) nn += vb_r[d] * vb_r[d];
      float n2 = nn + 1e-7f;
      float f = sqrtf(n2) / (1.0f + n2);
#pragma unroll
      for (int d = 0; d < 16; ++d) vb_r[d] *= f;
    }
  }

  constexpr int IPW = 32;
  constexpr int PF  = (MODE == 2) ? 2 : 4;   // prefetch depth

  const unsigned short* base = uh + (size_t)b * I_ * K_ + lane * 16;

  struct Row { ushort8_t lo, hi; };
  Row buf[PF];
#pragma unroll
  for (int p = 0; p < PF; ++p) {
    int ip = (i0 + p) & (I_ - 1);
    buf[p].lo = *(const ushort8_t*)(base + (size_t)ip * K_);
    buf[p].hi = *(const ushort8_t*)(base + (size_t)ip * K_ + 8);
  }

  float s_loc[16];
#pragma unroll
  for (int d = 0; d < 16; ++d) s_loc[d] = 0.f;

  for (int ii = 0; ii < IPW; ii += PF) {
#pragma unroll
    for (int p = 0; p < PF; ++p) {
      float u[16];
#pragma unroll
      for (int e = 0; e < 8; ++e) u[e]     = bf2f(buf[p].lo[e]);
#pragma unroll
      for (int e = 0; e < 8; ++e) u[8 + e] = bf2f(buf[p].hi[e]);

      int ip = (i0 + ii + p + PF) & (I_ - 1);
      buf[p].lo = *(const ushort8_t*)(base + (size_t)ip * K_);
      buf[p].hi = *(const ushort8_t*)(base + (size_t)ip * K_ + 8);

      if (MODE == 0) {
#pragma unroll
        for (int d = 0; d < 16; ++d) s_loc[d] += u[d];
      } else {
        float bl = 0.f;
#pragma unroll
        for (int d = 0; d < 16; ++d) bl += u[d] * va_r[d];
        if (MODE == 2) {
          float b2 = 0.f;
#pragma unroll
          for (int d = 0; d < 16; ++d) b2 += u[d] * vb_r[d];
          bl += b2;
        }
        float m = bl;
        m = fmaxf(m, __shfl_xor(m, 1));
        m = fmaxf(m, __shfl_xor(m, 2));
        m = fmaxf(m, __shfl_xor(m, 4));
        m = fmaxf(m, __shfl_xor(m, 8));
        m = fmaxf(m, __shfl_xor(m, 16));
        m = fmaxf(m, __shfl_xor(m, 32));
        float e = __expf(bl - m);
        float ss = e;
        ss += __shfl_xor(ss, 1);
        ss += __shfl_xor(ss, 2);
        ss += __shfl_xor(ss, 4);
        ss += __shfl_xor(ss, 8);
        ss += __shfl_xor(ss, 16);
        ss += __shfl_xor(ss, 32);
        float c = __fdividef(e, ss);
#pragma unroll
        for (int d = 0; d < 16; ++d) s_loc[d] += c * u[d];
      }
    }
  }

  if (MODE == 0) {
#pragma unroll
    for (int d = 0; d < 16; ++d) s_loc[d] *= (1.0f / 64.0f);
  }

  // block reduce (4 waves, same b) then atomics
  __shared__ float sred[4][64 * 17];
#pragma unroll
  for (int d = 0; d < 16; ++d) sred[wv][lane * 17 + d] = s_loc[d];
  __syncthreads();
#pragma unroll
  for (int e = 0; e < 4; ++e) {
    int idx = t * 4 + e;               // 0..1023
    int n = idx >> 4, d = idx & 15;
    float val = sred[0][n*17+d] + sred[1][n*17+d] + sred[2][n*17+d] + sred[3][n*17+d];
    atomicAdd(&s_out[(size_t)b * K_ + idx], val);
  }
}

// final output only: v = squash(s + bias)
__global__ __launch_bounds__(256) void squash_k(const float* __restrict__ s_in,
                                                const float* __restrict__ bias,
                                                float* __restrict__ v_out) {
  const int b = blockIdx.x, t = threadIdx.x, k0 = t * 4;
  float4 s = *(const float4*)&s_in[b * K_ + k0];
  float4 bb = *(const float4*)&bias[k0];
  s.x += bb.x; s.y += bb.y; s.z += bb.z; s.w += bb.w;
  float p = s.x * s.x + s.y * s.y + s.z * s.z + s.w * s.w;
  p += __shfl_xor(p, 1);
  p += __shfl_xor(p, 2);
  float n2 = p + 1e-7f;
  float nrm = sqrtf(n2);
  float f = nrm / (1.0f + n2);
  float4 o = {s.x * f, s.y * f, s.z * f, s.w * f};
  *(float4*)&v_out[b * K_ + k0] = o;
}

extern "C" void kernel_launch(void* const* d_in, const int* in_sizes, int n_in,
                              void* d_out, int out_size, void* d_ws, size_t ws_size,
                              hipStream_t stream) {
  const float* x    = (const float*)d_in[0];
  const float* W    = (const float*)d_in[1];
  const float* bias = (const float*)d_in[2];
  float* out = (float*)d_out;

  char* ws = (char*)d_ws;
  size_t off = 0;
  unsigned short* uh = (unsigned short*)(ws + off); off += (size_t)B_ * I_ * K_ * 2; // 268 MB
  float* s0 = (float*)(ws + off); off += (size_t)B_ * K_ * 4;
  float* s1 = (float*)(ws + off); off += (size_t)B_ * K_ * 4;
  float* s2 = (float*)(ws + off); off += (size_t)B_ * K_ * 4;

  if (ws_size < off)
    fprintf(stderr, "ClassCapsule: ws_size=%zu < needed=%zu — expect corruption\n", ws_size, off);

  hipMemsetAsync(s0, 0, (size_t)3 * B_ * K_ * 4, stream);  // s0,s1,s2 contiguous

  project_k<<<dim3(I_), dim3(256), 0, stream>>>(x, W, uh);

  route_k<0><<<dim3(1024), dim3(256), 0, stream>>>(uh, nullptr, nullptr, bias, s0);
  route_k<1><<<dim3(1024), dim3(256), 0, stream>>>(uh, s0, nullptr, bias, s1);
  route_k<2><<<dim3(1024), dim3(256), 0, stream>>>(uh, s0, s1, bias, s2);
  squash_k<<<dim3(B_), dim3(256), 0, stream>>>(s2, bias, out);
}